// Round 4
// baseline (51.865 us; speedup 1.0000x reference)
//
#include <hip/hip_runtime.h>

#define LOG2E    1.4426950408889634f
#define TWOLOG2E 2.8853900817779268f

// ---------------------------------------------------------------------------
// Kernel 1: projections  qp = (queries @ Wq^T) * 2log2e, kp likewise.
// W is staged in LDS (padded stride 130 -> 2-way bank conflicts only) so the
// per-lane row reads are ds_read_b128 instead of 512B-strided global loads.
// grid 512 (256 q-blocks + 256 k-blocks), 128 threads, 8 rows/block
// ---------------------------------------------------------------------------
__global__ __launch_bounds__(128) void proj_kernel(
    const float* __restrict__ queries, const float* __restrict__ keys,
    const float* __restrict__ Wq, const float* __restrict__ Wk,
    float* __restrict__ qp, float* __restrict__ kp)
{
    __shared__ float Ws[128 * 130];   // 66.6 KB, padded
    __shared__ float xs[8][128];      // 4 KB
    const int isK = blockIdx.x >= 256;
    const int rowBase = (blockIdx.x & 255) * 8;
    const float* __restrict__ x = isK ? keys : queries;
    const float* __restrict__ W = isK ? Wk : Wq;
    float* __restrict__ out = isK ? kp : qp;
    const int t = threadIdx.x;

    // stage W (64 KB) coalesced into padded LDS
    {
        const float4* wsrc = (const float4*)W;
        #pragma unroll
        for (int j = 0; j < 32; ++j) {
            int i = j * 128 + t;              // float4 index, coalesced
            float4 v = wsrc[i];
            int row = i >> 5;
            int c4  = (i & 31) * 4;
            *(float4*)&Ws[row * 130 + c4] = v;
        }
        const float4* src = (const float4*)(x + (size_t)rowBase * 128);
        float4* dst = (float4*)(&xs[0][0]);
        dst[t]       = src[t];
        dst[t + 128] = src[t + 128];
    }
    __syncthreads();

    const int wbase = t * 130;                // this thread's W row (padded)
    float acc[8] = {0,0,0,0,0,0,0,0};
    #pragma unroll 8
    for (int d4 = 0; d4 < 32; ++d4) {
        float4 w = *(const float4*)&Ws[wbase + d4 * 4];   // 2-way conflict: free
        #pragma unroll
        for (int r = 0; r < 8; ++r) {
            float4 xv = *(const float4*)&xs[r][d4 * 4];   // broadcast
            acc[r] = fmaf(xv.x, w.x, acc[r]);
            acc[r] = fmaf(xv.y, w.y, acc[r]);
            acc[r] = fmaf(xv.z, w.z, acc[r]);
            acc[r] = fmaf(xv.w, w.w, acc[r]);
        }
    }
    __syncthreads();
    #pragma unroll
    for (int r = 0; r < 8; ++r) xs[r][t] = acc[r] * TWOLOG2E;
    __syncthreads();
    {
        const float4* src = (const float4*)(&xs[0][0]);
        float4* dst = (float4*)(out + (size_t)rowBase * 128);
        dst[t]       = src[t];
        dst[t + 128] = src[t + 128];
    }
}

// ---------------------------------------------------------------------------
// Kernel 2: P[b][q][k] = exp(sum_h wv[h]*tanh(q+k)) and column partial sums
// Zpart[b][qt][k] = sum_{q in tile} P.   w*tanh(x) = w + (-2w)*rcp(e^2x + 1)
// grid (K/32=8, Q/32=8, B=8) = 512 blocks, 256 threads, 2q x 2k per thread
// ---------------------------------------------------------------------------
#define LDP 130

__global__ __launch_bounds__(256) void scoreP_kernel(
    const float* __restrict__ qp, const float* __restrict__ kp,
    const float* __restrict__ wv, float* __restrict__ P,
    float* __restrict__ Zpart)
{
    __shared__ float qs[32 * LDP];
    __shared__ float ks_[32 * LDP];
    __shared__ float w2s[128];          // -2 * wv
    __shared__ float part2[4][32];      // per-wave column partials

    const int kt = blockIdx.x, qt = blockIdx.y, b = blockIdx.z;
    const int t = threadIdx.x;

    const float4* qsrc = (const float4*)(qp + (size_t)(b * 256 + qt * 32) * 128);
    const float4* ksrc = (const float4*)(kp + (size_t)(b * 256 + kt * 32) * 128);
    {
        int r = t >> 3, c = (t & 7) * 16;
        #pragma unroll
        for (int j = 0; j < 4; ++j) {
            float4 v  = qsrc[t * 4 + j];
            *(float4*)&qs[r * LDP + c + j * 4] = v;
            float4 v2 = ksrc[t * 4 + j];
            *(float4*)&ks_[r * LDP + c + j * 4] = v2;
        }
        if (t < 32) {
            float4 w = ((const float4*)wv)[t];
            *(float4*)&w2s[t * 4] = make_float4(-2.f * w.x, -2.f * w.y,
                                                -2.f * w.z, -2.f * w.w);
        }
    }
    __syncthreads();

    // wsum = sum_h wv[h] = -0.5 * sum_h w2s[h]  (broadcast LDS reads)
    float wsum = 0.f;
    #pragma unroll 8
    for (int i = 0; i < 32; ++i) {
        float4 w = *(const float4*)&w2s[i * 4];
        wsum += (w.x + w.y) + (w.z + w.w);
    }
    wsum *= -0.5f;

    const int lk = (t & 15) * 2;
    const int lq = (t >> 4) * 2;

    float a00 = 0.f, a01 = 0.f, a10 = 0.f, a11 = 0.f;

    #pragma unroll 4
    for (int h = 0; h < 128; h += 4) {
        float4 w4 = *(const float4*)&w2s[h];
        float4 qa = *(const float4*)&qs[lq * LDP + h];
        float4 qb = *(const float4*)&qs[(lq + 1) * LDP + h];
        float4 ka = *(const float4*)&ks_[lk * LDP + h];
        float4 kb = *(const float4*)&ks_[(lk + 1) * LDP + h];
        const float wj[4]  = {w4.x, w4.y, w4.z, w4.w};
        const float qaj[4] = {qa.x, qa.y, qa.z, qa.w};
        const float qbj[4] = {qb.x, qb.y, qb.z, qb.w};
        const float kaj[4] = {ka.x, ka.y, ka.z, ka.w};
        const float kbj[4] = {kb.x, kb.y, kb.z, kb.w};
        #pragma unroll
        for (int j = 0; j < 4; ++j) {
            float r00 = __builtin_amdgcn_rcpf(__builtin_amdgcn_exp2f(qaj[j] + kaj[j]) + 1.0f);
            float r01 = __builtin_amdgcn_rcpf(__builtin_amdgcn_exp2f(qaj[j] + kbj[j]) + 1.0f);
            float r10 = __builtin_amdgcn_rcpf(__builtin_amdgcn_exp2f(qbj[j] + kaj[j]) + 1.0f);
            float r11 = __builtin_amdgcn_rcpf(__builtin_amdgcn_exp2f(qbj[j] + kbj[j]) + 1.0f);
            a00 = fmaf(wj[j], r00, a00);
            a01 = fmaf(wj[j], r01, a01);
            a10 = fmaf(wj[j], r10, a10);
            a11 = fmaf(wj[j], r11, a11);
        }
    }

    // s = wsum + acc; p = exp(s) = exp2(s * log2e)
    float p00 = __builtin_amdgcn_exp2f((a00 + wsum) * LOG2E);
    float p01 = __builtin_amdgcn_exp2f((a01 + wsum) * LOG2E);
    float p10 = __builtin_amdgcn_exp2f((a10 + wsum) * LOG2E);
    float p11 = __builtin_amdgcn_exp2f((a11 + wsum) * LOG2E);

    const int q = qt * 32 + lq;
    const int k = kt * 32 + lk;
    *(float2*)&P[((size_t)(b * 256 + q)) * 256 + k]     = make_float2(p00, p01);
    *(float2*)&P[((size_t)(b * 256 + q + 1)) * 256 + k] = make_float2(p10, p11);

    // column partial sums over this tile's 32 q rows: shuffle over the 4
    // lq-groups within each wave, then 4 waves combine through tiny LDS.
    float sa = p00 + p10;           // column lk
    float sb = p01 + p11;           // column lk+1
    sa += __shfl_xor(sa, 16, 64);
    sa += __shfl_xor(sa, 32, 64);
    sb += __shfl_xor(sb, 16, 64);
    sb += __shfl_xor(sb, 32, 64);
    const int wid = t >> 6;
    if ((t & 63) < 16) {
        part2[wid][lk]     = sa;
        part2[wid][lk + 1] = sb;
    }
    __syncthreads();
    if (t < 32) {
        float z = part2[0][t] + part2[1][t] + part2[2][t] + part2[3][t];
        Zpart[(size_t)b * 2048 + qt * 256 + kt * 32 + t] = z;
    }
}

// ---------------------------------------------------------------------------
// Kernel 3: out[b][q][d] = sum_k P[b,q,k] * c[b,k] * v[b,k,d],
//           c[b,k] = 1 / sum_qt Zpart[b][qt][k]
// grid B*(Q/4) = 512 blocks, 256 threads = 4 q-rows x 64 d-threads (float2)
// 8 waves/CU; within a wave all lanes share q -> V loads coalesced, L1 reuse
// across the 4 q-waves.
// ---------------------------------------------------------------------------
__global__ __launch_bounds__(256) void pv_kernel(
    const float* __restrict__ P, const float* __restrict__ Zpart,
    const float* __restrict__ values, float* __restrict__ out)
{
    __shared__ float ps[4][260];
    const int b  = blockIdx.x >> 6;
    const int q0 = (blockIdx.x & 63) * 4;
    const int t  = threadIdx.x;

    // phase A: p[q][k] = P * c for 4 q-rows x 256 k  (4 k per thread)
    {
        const int q  = t >> 6;          // 0..3
        const int k  = (t & 63) * 4;    // 0..252
        const float* zb = Zpart + (size_t)b * 2048 + k;
        float4 z = make_float4(0.f, 0.f, 0.f, 0.f);
        #pragma unroll
        for (int qt = 0; qt < 8; ++qt) {
            float4 a = *(const float4*)(zb + qt * 256);
            z.x += a.x; z.y += a.y; z.z += a.z; z.w += a.w;
        }
        const float* prow = P + ((size_t)(b * 256 + q0 + q)) * 256 + k;
        float4 s = *(const float4*)(prow);
        float4 r;
        r.x = s.x * __builtin_amdgcn_rcpf(z.x);
        r.y = s.y * __builtin_amdgcn_rcpf(z.y);
        r.z = s.z * __builtin_amdgcn_rcpf(z.z);
        r.w = s.w * __builtin_amdgcn_rcpf(z.w);
        *(float4*)&ps[q][k] = r;
    }
    __syncthreads();

    const int q  = t >> 6;     // 0..3  (whole wave shares q)
    const int d2 = t & 63;     // d = d2*2
    const float* vcol = values + (size_t)b * 256 * 128 + d2 * 2;

    float ax = 0.f, ay = 0.f;
    #pragma unroll 8
    for (int kk = 0; kk < 256; ++kk) {
        float p = ps[q][kk];
        float2 v = *(const float2*)(vcol + (size_t)kk * 128);
        ax = fmaf(p, v.x, ax);
        ay = fmaf(p, v.y, ay);
    }

    float* o = out + ((size_t)(b * 256 + q0 + q)) * 128 + d2 * 2;
    *(float2*)o = make_float2(ax, ay);
}

// ---------------------------------------------------------------------------
extern "C" void kernel_launch(void* const* d_in, const int* in_sizes, int n_in,
                              void* d_out, int out_size, void* d_ws, size_t ws_size,
                              hipStream_t stream)
{
    const float* queries = (const float*)d_in[0];  // (8,256,128)
    const float* keys    = (const float*)d_in[1];  // (8,256,128)
    const float* values  = (const float*)d_in[2];  // (8,256,128)
    const float* Wq      = (const float*)d_in[3];  // (128,128)
    const float* Wk      = (const float*)d_in[4];  // (128,128)
    const float* wv      = (const float*)d_in[5];  // (128,)
    float* out = (float*)d_out;                    // (8,256,128)

    float* ws = (float*)d_ws;
    float* qp    = ws;                   // 262144 floats (scaled by 2log2e)
    float* kp    = ws + 262144;          // 262144 floats (scaled by 2log2e)
    float* P     = ws + 524288;          // 524288 floats  exp(s)
    float* Zpart = ws + 1048576;         // 8*8*256 = 16384 floats

    proj_kernel<<<512, 128, 0, stream>>>(queries, keys, Wq, Wk, qp, kp);
    scoreP_kernel<<<dim3(8, 8, 8), 256, 0, stream>>>(qp, kp, wv, P, Zpart);
    pv_kernel<<<512, 256, 0, stream>>>(P, Zpart, values, out);
}